// Round 1
// baseline (77446.350 us; speedup 1.0000x reference)
//
#include <hip/hip_runtime.h>
#include <stdint.h>
#include <string.h>

// ---------------- problem constants ----------------
#define NV      4667
#define BB      4
#define TT      8
#define TPX     18
#define HID     16
#define NROOTS  500
#define NPATHS  7500
#define NEDGES  7000
#define NLEAF   4000
#define NPAD    4736   // 37*128
#define KPAD    4736

typedef __bf16 bf16;
typedef bf16  bf16x8 __attribute__((ext_vector_type(8)));
typedef float f32x4  __attribute__((ext_vector_type(4)));
typedef const void __attribute__((address_space(1))) gvoid;
typedef void       __attribute__((address_space(3))) svoid;

// ============================================================
// Host-side exact replication of np.random.RandomState(42) tree
// ============================================================
struct MT19937 {
    uint32_t mt[624]; int pos;
    void seed(uint32_t s) {
        for (int i = 0; i < 624; ++i) { mt[i] = s; s = 1812433253u * (s ^ (s >> 30)) + (uint32_t)i + 1u; }
        pos = 624;
    }
    uint32_t next() {
        if (pos >= 624) {
            for (int i = 0; i < 624; ++i) {
                uint32_t y = (mt[i] & 0x80000000u) | (mt[(i + 1) % 624] & 0x7fffffffu);
                uint32_t v = mt[(i + 397) % 624] ^ (y >> 1);
                if (y & 1u) v ^= 0x9908b0dfu;
                mt[i] = v;
            }
            pos = 0;
        }
        uint32_t y = mt[pos++];
        y ^= y >> 11; y ^= (y << 7) & 0x9d2c5680u; y ^= (y << 15) & 0xefc60000u; y ^= y >> 18;
        return y;
    }
    uint32_t interval(uint32_t mx) {  // uniform in [0, mx], legacy rk_interval
        if (!mx) return 0;
        uint32_t mask = mx;
        mask |= mask >> 1; mask |= mask >> 2; mask |= mask >> 4; mask |= mask >> 8; mask |= mask >> 16;
        uint32_t v;
        do { v = next() & mask; } while (v > mx);
        return v;
    }
};

struct TreeBlob {
    int path_node[NPATHS];     // node id of each path
    int leaf_start[NV + 1];    // CSR over leaf paths grouped by node
    int leaf_path[NLEAF];      // path indices (3500..7499)
};
static TreeBlob g_tree;

static void build_tree_host() {
    MT19937 rng; rng.seed(42);
    static int perm[NV];
    auto choice_take = [&](int* out, int k) {
        for (int i = 0; i < NV; ++i) perm[i] = i;
        for (int i = NV - 1; i >= 1; --i) {
            int j = (int)rng.interval((uint32_t)i);
            int t = perm[i]; perm[i] = perm[j]; perm[j] = t;
        }
        for (int i = 0; i < k; ++i) out[i] = perm[i];
    };
    int np_ = 0;
    int roots[NROOTS];
    choice_take(roots, NROOTS);
    for (int i = 0; i < NROOTS; ++i) g_tree.path_node[np_++] = roots[i];
    int prev_cnt = NROOTS;
    for (int lvl = 0; lvl < 3; ++lvl) {
        int kids[2];
        for (int p = 0; p < prev_cnt; ++p) {
            choice_take(kids, 2);
            g_tree.path_node[np_++] = kids[0];
            g_tree.path_node[np_++] = kids[1];
        }
        prev_cnt *= 2;
    }
    // leaves: paths 3500..7499
    static int cnt[NV], cur[NV];
    memset(cnt, 0, sizeof(cnt));
    for (int l = 0; l < NLEAF; ++l) cnt[g_tree.path_node[3500 + l]]++;
    g_tree.leaf_start[0] = 0;
    for (int n = 0; n < NV; ++n) g_tree.leaf_start[n + 1] = g_tree.leaf_start[n] + cnt[n];
    for (int n = 0; n < NV; ++n) cur[n] = g_tree.leaf_start[n];
    for (int l = 0; l < NLEAF; ++l) {
        int n = g_tree.path_node[3500 + l];
        g_tree.leaf_path[cur[n]++] = 3500 + l;
    }
}

// ============================================================
// Kernels
// ============================================================

// TimeBlock x3 + concat -> x [B,NV,18,16] f32
__global__ void k_timeblock(const float* __restrict__ X, const float* __restrict__ Xd,
                            const float* __restrict__ Xw,
                            const float* __restrict__ w1, const float* __restrict__ b1,
                            const float* __restrict__ w2, const float* __restrict__ b2,
                            float* __restrict__ x) {
    int idx = blockIdx.x * 256 + threadIdx.x;     // (b,n,g,t)
    if (idx >= BB * NV * 18) return;
    int t = idx % 6;
    int g = (idx / 6) % 3;
    int n = (idx / 18) % NV;
    int b = idx / (18 * NV);
    const float* Xg = (g == 0) ? X : (g == 1) ? Xd : Xw;
    const float* p = Xg + (((size_t)b * NV + n) * TT + t) * 2;
    float v[6];
#pragma unroll
    for (int kk = 0; kk < 3; ++kk) { v[kk * 2 + 0] = p[kk * 2 + 0]; v[kk * 2 + 1] = p[kk * 2 + 1]; }
    float* xo = x + (((size_t)b * NV + n) * TPX + (g * 6 + t)) * HID;
#pragma unroll
    for (int o = 0; o < 16; ++o) {
        float c1 = b1[o], c2 = b2[o];
#pragma unroll
        for (int ci = 0; ci < 2; ++ci)
#pragma unroll
            for (int kk = 0; kk < 3; ++kk) {
                float xv = v[kk * 2 + ci];
                c1 += xv * w1[(o * 2 + ci) * 3 + kk];
                c2 += xv * w2[(o * 2 + ci) * 3 + kk];
            }
        xo[o] = c1 * (1.0f / (1.0f + __expf(-c2)));
    }
}

// lhs[b,n,c], rhs[b,n,c]
__global__ void k_lhsrhs(const float* __restrict__ x, const float* __restrict__ W1,
                         const float* __restrict__ W2, const float* __restrict__ W3,
                         float* __restrict__ lhs, float* __restrict__ rhs) {
    int idx = blockIdx.x * 256 + threadIdx.x;
    if (idx >= BB * NV) return;
    const float* xp = x + (size_t)idx * TPX * HID;
    float l[16], r[16];
#pragma unroll
    for (int c = 0; c < 16; ++c) { l[c] = 0.f; r[c] = 0.f; }
    for (int t = 0; t < TPX; ++t) {
        float xt = 0.f, w3 = W3[t];
#pragma unroll
        for (int c = 0; c < 16; ++c) { float xv = xp[t * 16 + c]; xt += xv * W1[c]; r[c] += w3 * xv; }
#pragma unroll
        for (int c = 0; c < 16; ++c) l[c] += xt * W2[t * 16 + c];
    }
    float* lo = lhs + (size_t)idx * 16;
    float* ro = rhs + (size_t)idx * 16;
#pragma unroll
    for (int c = 0; c < 16; ++c) { lo[c] = l[c]; ro[c] = r[c]; }
}

// Vs f32 -> bf16, zero-padded to NPAD x KPAD
__global__ void k_vsb(const float* __restrict__ Vs, bf16* __restrict__ VsB) {
    size_t idx = (size_t)blockIdx.x * 256 + threadIdx.x;
    if (idx >= (size_t)NPAD * KPAD) return;
    int m = (int)(idx % KPAD);
    int n = (int)(idx / KPAD);
    float v = (n < NV && m < NV) ? Vs[(size_t)n * NV + m] : 0.f;
    VsB[idx] = (bf16)v;
}

// sigT[b][k][m] = sigmoid(lhs[b,m,:].rhs[b,k,:] + bs[m,k]); zero pads.
__global__ void k_sig(const float* __restrict__ lhs, const float* __restrict__ rhs,
                      const float* __restrict__ bs, bf16* __restrict__ sigT) {
    int b = blockIdx.z;
    int k0 = blockIdx.y * 64, m0 = blockIdx.x * 64;
    __shared__ float Ls[64][17];
    __shared__ float Rs[64][17];
    int t = threadIdx.x;
    for (int i = t; i < 64 * 16; i += 256) {
        int rr = i >> 4, cc = i & 15;
        int mg = m0 + rr;
        Ls[rr][cc] = (mg < NV) ? lhs[((size_t)b * NV + mg) * 16 + cc] : 0.f;
        int kg = k0 + rr;
        Rs[rr][cc] = (kg < NV) ? rhs[((size_t)b * NV + kg) * 16 + cc] : 0.f;
    }
    __syncthreads();
    int ml = t & 63, kc = t >> 6;
    int mg = m0 + ml;
    float lv[16];
#pragma unroll
    for (int c = 0; c < 16; ++c) lv[c] = Ls[ml][c];
#pragma unroll
    for (int kk = 0; kk < 16; ++kk) {
        int kl = kc * 16 + kk;
        int kg = k0 + kl;
        float s = 0.f;
        if (mg < NV && kg < NV) {
            float dot = 0.f;
#pragma unroll
            for (int c = 0; c < 16; ++c) dot += lv[c] * Rs[kl][c];
            float pv = dot + bs[(size_t)mg * NV + kg];
            s = 1.0f / (1.0f + __expf(-pv));
        }
        sigT[((size_t)b * NPAD + kg) * KPAD + mg] = (bf16)s;
    }
}

// S = VsB @ sigT[b]^T (B^T layout), fused exp + column-sum (softmax denom).
__global__ __launch_bounds__(256, 2)
void k_gemm(const bf16* __restrict__ VsB, const bf16* __restrict__ sigT,
            float* __restrict__ colsum) {
    int b = blockIdx.z;
    int n0 = blockIdx.x * 128;   // output rows (n)
    int k0 = blockIdx.y * 128;   // output cols (k)
    const bf16* Bp = sigT + (size_t)b * NPAD * KPAD;

    __shared__ __align__(16) bf16 As[128 * 32];
    __shared__ __align__(16) bf16 Bs[128 * 32];

    int lane = threadIdx.x & 63;
    int wave = threadIdx.x >> 6;
    int wr = wave >> 1, wc = wave & 1;
    int lr = lane & 15, lg = lane >> 4;

    f32x4 acc[4][4];
#pragma unroll
    for (int i = 0; i < 4; ++i)
#pragma unroll
        for (int j = 0; j < 4; ++j) acc[i][j] = f32x4{0.f, 0.f, 0.f, 0.f};

    int srow0 = lane >> 2;
    int scol = (lane & 3) * 8;

    for (int kk0 = 0; kk0 < KPAD; kk0 += 32) {
        __syncthreads();  // protect LDS from previous iteration's reads
        for (int s = wave; s < 8; s += 4) {
            int row = s * 16 + srow0;
            const bf16* ga = VsB + (size_t)(n0 + row) * KPAD + kk0 + scol;
            const bf16* gb = Bp  + (size_t)(k0 + row) * KPAD + kk0 + scol;
            __builtin_amdgcn_global_load_lds((gvoid*)ga, (svoid*)&As[s * 512], 16, 0, 0);
            __builtin_amdgcn_global_load_lds((gvoid*)gb, (svoid*)&Bs[s * 512], 16, 0, 0);
        }
        __syncthreads();  // compiler drains vmcnt before s_barrier
        bf16x8 af[4], bg[4];
#pragma unroll
        for (int i = 0; i < 4; ++i) af[i] = *(const bf16x8*)&As[(wr * 64 + i * 16 + lr) * 32 + lg * 8];
#pragma unroll
        for (int j = 0; j < 4; ++j) bg[j] = *(const bf16x8*)&Bs[(wc * 64 + j * 16 + lr) * 32 + lg * 8];
#pragma unroll
        for (int i = 0; i < 4; ++i)
#pragma unroll
            for (int j = 0; j < 4; ++j)
                acc[i][j] = __builtin_amdgcn_mfma_f32_16x16x32_bf16(af[i], bg[j], acc[i][j], 0, 0, 0);
    }

    // epilogue: masked exp + per-column partial sums -> atomic colsum
#pragma unroll
    for (int j = 0; j < 4; ++j) {
        int col = k0 + wc * 64 + j * 16 + lr;
        float csum = 0.f;
#pragma unroll
        for (int i = 0; i < 4; ++i) {
            int rowb = n0 + wr * 64 + i * 16 + lg * 4;
#pragma unroll
            for (int r = 0; r < 4; ++r) {
                float vv = acc[i][j][r];
                float e = ((rowb + r) < NV && col < NV) ? __expf(vv) : 0.f;
                csum += e;
            }
        }
        csum += __shfl_xor(csum, 16);
        csum += __shfl_xor(csum, 32);
        if (lane < 16 && col < NV) atomicAdd(&colsum[(size_t)b * NV + col], csum);
    }
}

// per-edge: S[b,pn,cn] dot + A = exp/colsum
__global__ void k_edge(const bf16* __restrict__ VsB, const bf16* __restrict__ sigT,
                       const float* __restrict__ colsum, const int* __restrict__ path_node,
                       float* __restrict__ a_edge) {
    int g = blockIdx.x;            // global edge 0..6999
    int b = threadIdx.x >> 6;
    int lane = threadIdx.x & 63;
    int e, pbase, cbase;
    if (g < 1000)      { e = g;        pbase = 0;    cbase = 500;  }
    else if (g < 3000) { e = g - 1000; pbase = 500;  cbase = 1500; }
    else               { e = g - 3000; pbase = 1500; cbase = 3500; }
    int pn = path_node[pbase + (e >> 1)];
    int cn = path_node[cbase + e];
    const bf16* va = VsB + (size_t)pn * KPAD;
    const bf16* vb = sigT + ((size_t)b * NPAD + cn) * KPAD;
    float s = 0.f;
    for (int i = lane * 8; i < KPAD; i += 512) {
        bf16x8 A = *(const bf16x8*)&va[i];
        bf16x8 Bv = *(const bf16x8*)&vb[i];
#pragma unroll
        for (int q = 0; q < 8; ++q) s += (float)A[q] * (float)Bv[q];
    }
#pragma unroll
    for (int off = 32; off; off >>= 1) s += __shfl_xor(s, off);
    if (lane == 0) {
        a_edge[(size_t)g * BB + b] = __expf(s) / colsum[(size_t)b * NV + cn];
    }
}

// H[p] = x[:, roots[p]] for p < 500
__global__ void k_root(const float* __restrict__ x, const int* __restrict__ path_node,
                       float* __restrict__ H) {
    int idx = blockIdx.x * 256 + threadIdx.x;
    if (idx >= NROOTS * BB * 288) return;
    int d = idx % 288;
    int b = (idx / 288) % BB;
    int p = idx / (288 * BB);
    int n = path_node[p];
    H[((size_t)p * BB + b) * 288 + d] = x[((size_t)b * NV + n) * 288 + d];
}

// one tree level: H[child] = (H[parent] @ fc_w^T + fc_b) * a + x[:,cn]
__global__ void k_level(const float* __restrict__ x, const int* __restrict__ path_node,
                        const float* __restrict__ fcw, const float* __restrict__ fcb,
                        const float* __restrict__ a_edge, float* __restrict__ H,
                        int E, int pbase, int cbase, int gbase) {
    int idx = blockIdx.x * 256 + threadIdx.x;
    if (idx >= E * BB * 288) return;
    int d = idx & 15;
    int t = (idx >> 4) % TPX;
    int b = (idx / (16 * TPX)) % BB;
    int e = idx / (16 * TPX * BB);
    int pp = pbase + (e >> 1);
    int cp = cbase + e;
    const float* hp = &H[(((size_t)pp * BB + b) * TPX + t) * HID];
    float acc = fcb[d];
#pragma unroll
    for (int c = 0; c < 16; ++c) acc += hp[c] * fcw[d * 16 + c];
    float a = a_edge[(size_t)(gbase + e) * BB + b];
    int cn = path_node[cp];
    float xv = x[(((size_t)b * NV + cn) * TPX + t) * HID + d];
    H[(((size_t)cp * BB + b) * TPX + t) * HID + d] = acc * a + xv;
}

// leaf mean-pool per node; fallback to x
__global__ void k_pool(const float* __restrict__ x, const float* __restrict__ H,
                       const int* __restrict__ leaf_start, const int* __restrict__ leaf_path,
                       float* __restrict__ out) {
    int n = blockIdx.x;
    int s = leaf_start[n], epos = leaf_start[n + 1];
    int cnt = epos - s;
    for (int idx = threadIdx.x; idx < BB * 288; idx += 256) {
        int b = idx / 288, d = idx % 288;
        float v;
        if (cnt == 0) {
            v = x[((size_t)b * NV + n) * 288 + d];
        } else {
            float sum = 0.f;
            for (int l = s; l < epos; ++l) {
                int p = leaf_path[l];
                sum += H[((size_t)p * BB + b) * 288 + d];
            }
            v = sum / (float)cnt;
        }
        out[((size_t)b * NV + n) * 288 + d] = v;
    }
}

// ============================================================
// Launch
// ============================================================
extern "C" void kernel_launch(void* const* d_in, const int* in_sizes, int n_in,
                              void* d_out, int out_size, void* d_ws, size_t ws_size,
                              hipStream_t stream) {
    const float* X   = (const float*)d_in[0];
    const float* Xd  = (const float*)d_in[1];
    const float* Xw  = (const float*)d_in[2];
    /* d_in[3] mask unused */
    const float* c1w = (const float*)d_in[4];
    const float* c1b = (const float*)d_in[5];
    const float* c2w = (const float*)d_in[6];
    const float* c2b = (const float*)d_in[7];
    const float* W1  = (const float*)d_in[8];
    const float* W2  = (const float*)d_in[9];
    const float* W3  = (const float*)d_in[10];
    const float* bs  = (const float*)d_in[11];
    const float* Vs  = (const float*)d_in[12];
    const float* fcw = (const float*)d_in[13];
    const float* fcb = (const float*)d_in[14];
    float* out = (float*)d_out;

    build_tree_host();  // deterministic constants, recomputed every call

    char* w = (char*)d_ws;
    auto alloc = [&](size_t bytes) { char* p = w; w += (bytes + 255) & ~(size_t)255; return p; };
    float* x      = (float*)alloc((size_t)BB * NV * 288 * 4);
    float* lhs    = (float*)alloc((size_t)BB * NV * 16 * 4);
    float* rhs    = (float*)alloc((size_t)BB * NV * 16 * 4);
    float* colsum = (float*)alloc((size_t)BB * NV * 4);
    float* aedge  = (float*)alloc((size_t)NEDGES * BB * 4);
    float* H      = (float*)alloc((size_t)NPATHS * BB * 288 * 4);
    int*   dtree  = (int*)alloc(sizeof(TreeBlob));
    bf16*  VsB    = (bf16*)alloc((size_t)NPAD * KPAD * 2);
    bf16*  sigT   = (bf16*)alloc((size_t)BB * NPAD * KPAD * 2);

    int* d_path   = dtree;
    int* d_lstart = dtree + NPATHS;
    int* d_lpath  = d_lstart + (NV + 1);

    hipMemcpyAsync(dtree, &g_tree, sizeof(TreeBlob), hipMemcpyHostToDevice, stream);
    hipMemsetAsync(colsum, 0, (size_t)BB * NV * 4, stream);

    k_timeblock<<<(BB * NV * 18 + 255) / 256, 256, 0, stream>>>(X, Xd, Xw, c1w, c1b, c2w, c2b, x);
    k_lhsrhs<<<(BB * NV + 255) / 256, 256, 0, stream>>>(x, W1, W2, W3, lhs, rhs);
    k_vsb<<<(int)(((size_t)NPAD * KPAD + 255) / 256), 256, 0, stream>>>(Vs, VsB);
    dim3 sgrid(NPAD / 64, NPAD / 64, BB);
    k_sig<<<sgrid, 256, 0, stream>>>(lhs, rhs, bs, sigT);
    dim3 ggrid(NPAD / 128, NPAD / 128, BB);
    k_gemm<<<ggrid, 256, 0, stream>>>(VsB, sigT, colsum);
    k_edge<<<NEDGES, 256, 0, stream>>>(VsB, sigT, colsum, d_path, aedge);
    k_root<<<(NROOTS * BB * 288 + 255) / 256, 256, 0, stream>>>(x, d_path, H);
    k_level<<<(1000 * BB * 288 + 255) / 256, 256, 0, stream>>>(x, d_path, fcw, fcb, aedge, H, 1000, 0, 500, 0);
    k_level<<<(2000 * BB * 288 + 255) / 256, 256, 0, stream>>>(x, d_path, fcw, fcb, aedge, H, 2000, 500, 1500, 1000);
    k_level<<<(4000 * BB * 288 + 255) / 256, 256, 0, stream>>>(x, d_path, fcw, fcb, aedge, H, 4000, 1500, 3500, 3000);
    k_pool<<<NV, 256, 0, stream>>>(x, H, d_lstart, d_lpath, out);
}